// Round 1
// baseline (101.904 us; speedup 1.0000x reference)
//
#include <hip/hip_runtime.h>
#include <math.h>

#define KW 11
#define HALO 10
#define TX 256
#define TY 32
#define BATCH 32
#define HH 512
#define WW 512
#define OH 502
#define OW 502
#define NBX 2
#define NBY 16
#define C3V 1.0e-4f

// main kernel: separable gaussian conv of 5 channels + fused SSIM-s + block partial sum
__global__ __launch_bounds__(TX) void ssim_strip_kernel(
    const float* __restrict__ in1,
    const float* __restrict__ in2,
    const float* __restrict__ win,
    double* __restrict__ partials)
{
    __shared__ float sh1[2][TX + 16];
    __shared__ float sh2[2][TX + 16];
    __shared__ double sred[4];

    const int t = threadIdx.x;
    const int x0 = blockIdx.x * TX;
    const int y0 = blockIdx.y * TY;
    const int img = blockIdx.z;

    const int nx = min(TX, OW - x0);
    const int ny = min(TY, OH - y0);
    const int totcols = nx + HALO;
    const int rows = ny + HALO;

    // extract separable 1D gaussian: w2d[i][j] = g[i]*g[j]
    float gv[KW];
    {
        float c = sqrtf(win[5 * KW + 5]);
        #pragma unroll
        for (int i = 0; i < KW; ++i) gv[i] = win[i * KW + 5] / c;
    }

    const float* p1 = in1 + (size_t)img * HH * WW;
    const float* p2 = in2 + (size_t)img * HH * WW;

    // vertical sliding accumulators, 5 channels x 11 slots, register-rotated
    float acc0[KW], acc1[KW], acc2[KW], acc3[KW], acc4[KW];
    #pragma unroll
    for (int i = 0; i < KW; ++i) {
        acc0[i] = 0.f; acc1[i] = 0.f; acc2[i] = 0.f; acc3[i] = 0.f; acc4[i] = 0.f;
    }

    double tsum = 0.0;

    int yr = 0;
    while (yr < rows) {
        #pragma unroll
        for (int p = 0; p < KW; ++p, ++yr) {
            if (yr < rows) {
                const int buf = yr & 1;
                const float* r1 = p1 + (size_t)(y0 + yr) * WW + x0;
                const float* r2 = p2 + (size_t)(y0 + yr) * WW + x0;
                if (t < totcols)      { sh1[buf][t] = r1[t];           sh2[buf][t] = r2[t]; }
                if (t + TX < totcols) { sh1[buf][t + TX] = r1[t + TX]; sh2[buf][t + TX] = r2[t + TX]; }
                __syncthreads();

                if (t < nx) {
                    // horizontal 11-tap conv of the 5 channels (products on the fly)
                    float h0 = 0.f, h1 = 0.f, h2 = 0.f, h3 = 0.f, h4 = 0.f;
                    #pragma unroll
                    for (int j = 0; j < KW; ++j) {
                        float a = sh1[buf][t + j];
                        float b = sh2[buf][t + j];
                        float ga = gv[j] * a;
                        float gb = gv[j] * b;
                        h0 += ga;
                        h1 += gb;
                        h2 = fmaf(ga, a, h2);
                        h3 = fmaf(gb, b, h3);
                        h4 = fmaf(ga, b, h4);
                    }
                    // vertical accumulate: at phase p, slot j lives in register (j+p)%11.
                    // register r is slot (r-p)%11; weight for this row into slot j is g[10-j].
                    #pragma unroll
                    for (int r = 0; r < KW; ++r) {
                        const int j = (r - p + KW) % KW;
                        const float w = gv[HALO - j];
                        acc0[r] = fmaf(w, h0, acc0[r]);
                        acc1[r] = fmaf(w, h1, acc1[r]);
                        acc2[r] = fmaf(w, h2, acc2[r]);
                        acc3[r] = fmaf(w, h3, acc3[r]);
                        acc4[r] = fmaf(w, h4, acc4[r]);
                    }
                    // slot 0 = register p completes at this row (output row yr-10)
                    if (yr >= HALO) {
                        const float mu1 = acc0[p], mu2 = acc1[p];
                        const float e11 = acc2[p], e22 = acc3[p], e12 = acc4[p];
                        const float s1q = fmaf(-mu1, mu1, e11);
                        const float s2q = fmaf(-mu2, mu2, e22);
                        const float s12 = fmaf(-mu1, mu2, e12);
                        const float den = sqrtf(fabsf(s1q)) * sqrtf(fabsf(s2q)) + C3V;
                        const float s = (s12 + C3V) / den;
                        tsum += (double)s;
                    }
                    // register p becomes slot 10 next phase: reset
                    acc0[p] = 0.f; acc1[p] = 0.f; acc2[p] = 0.f; acc3[p] = 0.f; acc4[p] = 0.f;
                }
            }
        }
    }

    // block reduction (deterministic): wave shuffle then LDS across the 4 waves
    #pragma unroll
    for (int off = 32; off > 0; off >>= 1)
        tsum += __shfl_down(tsum, off, 64);
    const int wid = t >> 6;
    const int lane = t & 63;
    if (lane == 0) sred[wid] = tsum;
    __syncthreads();
    if (t == 0) {
        double bsum = sred[0] + sred[1] + sred[2] + sred[3];
        const int bid = (img * NBY + blockIdx.y) * NBX + blockIdx.x;
        partials[bid] = bsum;
    }
}

// deterministic final reduce of the 1024 block partials -> mean
__global__ __launch_bounds__(256) void ssim_reduce_kernel(
    const double* __restrict__ partials, float* __restrict__ out)
{
    __shared__ double sred[4];
    const int n = BATCH * NBY * NBX;
    double s = 0.0;
    for (int i = threadIdx.x; i < n; i += 256) s += partials[i];
    #pragma unroll
    for (int off = 32; off > 0; off >>= 1)
        s += __shfl_down(s, off, 64);
    const int wid = threadIdx.x >> 6;
    const int lane = threadIdx.x & 63;
    if (lane == 0) sred[wid] = s;
    __syncthreads();
    if (threadIdx.x == 0) {
        double total = sred[0] + sred[1] + sred[2] + sred[3];
        out[0] = (float)(total / ((double)BATCH * OH * OW));
    }
}

extern "C" void kernel_launch(void* const* d_in, const int* in_sizes, int n_in,
                              void* d_out, int out_size, void* d_ws, size_t ws_size,
                              hipStream_t stream) {
    const float* in1 = (const float*)d_in[0];
    const float* in2 = (const float*)d_in[1];
    const float* win = (const float*)d_in[2];
    float* out = (float*)d_out;
    double* partials = (double*)d_ws;  // 1024 doubles = 8 KB

    dim3 grid(NBX, NBY, BATCH);
    dim3 block(TX);
    ssim_strip_kernel<<<grid, block, 0, stream>>>(in1, in2, win, partials);
    ssim_reduce_kernel<<<1, 256, 0, stream>>>(partials, out);
}

// Round 2
// 69.397 us; speedup vs baseline: 1.4684x; 1.4684x over previous
//
#include <hip/hip_runtime.h>
#include <math.h>

#define KW 11
#define HALO 10
#define TX 64
#define TY 32
#define BATCH 32
#define HH 512
#define WW 512
#define OH 502
#define OW 502
#define NBX 8     // ceil(502/64)
#define NBY 16    // ceil(502/32)
#define NBLK (BATCH * NBY * NBX)
#define C3V 1.0e-4f
#define SW 80     // staged row width in floats (20 float4)
#define NQ 20     // float4 quads per staged row

// One wave per block. Each thread owns one output column; 32 output rows per
// block streamed vertically with a 5-channel x 11-slot register-rotated
// sliding accumulator. LDS staging in 11-row chunks (phase-aligned), float4.
__global__ __launch_bounds__(TX) void ssim_strip_kernel(
    const float* __restrict__ in1,
    const float* __restrict__ in2,
    const float* __restrict__ win,
    double* __restrict__ partials)
{
    __shared__ float sh1[KW][SW];
    __shared__ float sh2[KW][SW];

    const int t = threadIdx.x;
    const int x0 = blockIdx.x * TX;
    const int y0 = blockIdx.y * TY;
    const int img = blockIdx.z;

    const int nx = min(TX, OW - x0);   // 64, last block 54
    const int ny = min(TY, OH - y0);   // 32, last strip 22
    const int rows = ny + HALO;

    // extract separable 1D gaussian: w2d[i][j] = g[i]*g[j]
    float gv[KW];
    {
        float c = sqrtf(win[5 * KW + 5]);
        #pragma unroll
        for (int i = 0; i < KW; ++i) gv[i] = win[i * KW + 5] / c;
    }

    const float* p1 = in1 + (size_t)img * HH * WW;
    const float* p2 = in2 + (size_t)img * HH * WW;

    float acc0[KW], acc1[KW], acc2[KW], acc3[KW], acc4[KW];
    #pragma unroll
    for (int i = 0; i < KW; ++i) {
        acc0[i] = 0.f; acc1[i] = 0.f; acc2[i] = 0.f; acc3[i] = 0.f; acc4[i] = 0.f;
    }

    double tsum = 0.0;
    const int nchunks = (rows + KW - 1) / KW;   // 3 or 4

    for (int c = 0; c < nchunks; ++c) {
        __syncthreads();   // previous chunk's reads complete (trivial: 1 wave)
        // stage 11 rows x 20 float4 x 2 inputs
        #pragma unroll
        for (int k = 0; k < (KW * NQ + TX - 1) / TX; ++k) {
            const int i = t + k * TX;
            if (i < KW * NQ) {
                const int r = i / NQ;
                const int q = i - r * NQ;
                const int yr = c * KW + r;
                const int col = x0 + 4 * q;
                if (yr < rows && col < WW) {
                    const size_t off = (size_t)(y0 + yr) * WW + col;
                    const float4 v1 = *(const float4*)(p1 + off);
                    const float4 v2 = *(const float4*)(p2 + off);
                    *(float4*)&sh1[r][4 * q] = v1;
                    *(float4*)&sh2[r][4 * q] = v2;
                }
            }
        }
        __syncthreads();

        #pragma unroll
        for (int p = 0; p < KW; ++p) {      // phase == row-in-chunk (chunk==KW)
            const int yr = c * KW + p;
            if (yr < rows && t < nx) {
                // horizontal 11-tap conv of the 5 channels, products on the fly
                float h0 = 0.f, h1 = 0.f, h2 = 0.f, h3 = 0.f, h4 = 0.f;
                #pragma unroll
                for (int j = 0; j < KW; ++j) {
                    const float a = sh1[p][t + j];
                    const float b = sh2[p][t + j];
                    const float ga = gv[j] * a;
                    const float gb = gv[j] * b;
                    h0 += ga;
                    h1 += gb;
                    h2 = fmaf(ga, a, h2);
                    h3 = fmaf(gb, b, h3);
                    h4 = fmaf(ga, b, h4);
                }
                // vertical accumulate: at phase p, slot j lives in register (j+p)%11
                #pragma unroll
                for (int r2 = 0; r2 < KW; ++r2) {
                    const int j = (r2 - p + KW) % KW;
                    const float w = gv[HALO - j];
                    acc0[r2] = fmaf(w, h0, acc0[r2]);
                    acc1[r2] = fmaf(w, h1, acc1[r2]);
                    acc2[r2] = fmaf(w, h2, acc2[r2]);
                    acc3[r2] = fmaf(w, h3, acc3[r2]);
                    acc4[r2] = fmaf(w, h4, acc4[r2]);
                }
                // slot 0 (= register p) completes at this row -> output row yr-10
                if (yr >= HALO) {
                    const float mu1 = acc0[p], mu2 = acc1[p];
                    const float e11 = acc2[p], e22 = acc3[p], e12 = acc4[p];
                    const float s1q = fmaf(-mu1, mu1, e11);
                    const float s2q = fmaf(-mu2, mu2, e22);
                    const float s12 = fmaf(-mu1, mu2, e12);
                    const float den = __builtin_amdgcn_sqrtf(fabsf(s1q)) *
                                      __builtin_amdgcn_sqrtf(fabsf(s2q)) + C3V;
                    const float s = (s12 + C3V) * __builtin_amdgcn_rcpf(den);
                    tsum += (double)s;
                }
                acc0[p] = 0.f; acc1[p] = 0.f; acc2[p] = 0.f;
                acc3[p] = 0.f; acc4[p] = 0.f;
            }
        }
    }

    // single-wave deterministic reduction
    #pragma unroll
    for (int off = 32; off > 0; off >>= 1)
        tsum += __shfl_down(tsum, off, 64);
    if (t == 0) {
        const int bid = (img * NBY + blockIdx.y) * NBX + blockIdx.x;
        partials[bid] = tsum;
    }
}

// deterministic final reduce of the 4096 block partials -> mean
__global__ __launch_bounds__(256) void ssim_reduce_kernel(
    const double* __restrict__ partials, float* __restrict__ out)
{
    __shared__ double sred[4];
    double s = 0.0;
    for (int i = threadIdx.x; i < NBLK; i += 256) s += partials[i];
    #pragma unroll
    for (int off = 32; off > 0; off >>= 1)
        s += __shfl_down(s, off, 64);
    const int wid = threadIdx.x >> 6;
    const int lane = threadIdx.x & 63;
    if (lane == 0) sred[wid] = s;
    __syncthreads();
    if (threadIdx.x == 0) {
        const double total = sred[0] + sred[1] + sred[2] + sred[3];
        out[0] = (float)(total / ((double)BATCH * OH * OW));
    }
}

extern "C" void kernel_launch(void* const* d_in, const int* in_sizes, int n_in,
                              void* d_out, int out_size, void* d_ws, size_t ws_size,
                              hipStream_t stream) {
    const float* in1 = (const float*)d_in[0];
    const float* in2 = (const float*)d_in[1];
    const float* win = (const float*)d_in[2];
    float* out = (float*)d_out;
    double* partials = (double*)d_ws;  // 4096 doubles = 32 KB

    dim3 grid(NBX, NBY, BATCH);
    dim3 block(TX);
    ssim_strip_kernel<<<grid, block, 0, stream>>>(in1, in2, win, partials);
    ssim_reduce_kernel<<<1, 256, 0, stream>>>(partials, out);
}

// Round 3
// 63.332 us; speedup vs baseline: 1.6090x; 1.0958x over previous
//
#include <hip/hip_runtime.h>
#include <math.h>

#define KW 11
#define HALO 10
#define TY 32
#define BATCH 32
#define HH 512
#define WW 512
#define OH 502
#define OW 502
#define NSX 8          // 64-col strips covering 502 cols (last strip 54)
#define WPB 4          // waves per block, fully independent
#define NBX 2          // NSX / WPB
#define NBY 16         // ceil(502/32)
#define NWAVE (BATCH * NBY * NSX)   // 4096 partials
#define C3V 1.0e-4f
#define SW 80          // staged row width (floats)
#define NQ 20          // float4 quads per staged row

// 4 independent waves per block; each wave owns a 64-col strip, streams 42
// input rows with per-row double-buffered wave-private LDS staging (no
// __syncthreads anywhere), h-conv + register-rotated vertical sliding
// accumulators, fused SSIM-s epilogue, per-wave double partial sum.
__global__ __launch_bounds__(256) void ssim_strip_kernel(
    const float* __restrict__ in1,
    const float* __restrict__ in2,
    const float* __restrict__ win,
    double* __restrict__ partials)
{
    __shared__ float sh[WPB][2][2][SW];   // [wave][buf][input][col]

    const int t = threadIdx.x;
    const int wid = t >> 6;
    const int lane = t & 63;
    const int strip = blockIdx.x * WPB + wid;
    const int x0 = strip * 64;
    const int y0 = blockIdx.y * TY;
    const int img = blockIdx.z;

    const int nx = min(64, OW - x0);     // 64, last strip 54
    const int ny = min(TY, OH - y0);     // 32, last y-strip 22
    const int rows = ny + HALO;          // 42 or 32

    // separable 1D gaussian from the 2D window: w2d[i][j] = g[i]*g[j]
    float gv[KW];
    {
        const float c = sqrtf(win[5 * KW + 5]);
        #pragma unroll
        for (int i = 0; i < KW; ++i) gv[i] = win[i * KW + 5] / c;
    }

    // staging roles: lanes 0..19 -> in1 quad q=lane; lanes 20..39 -> in2
    const bool stager = lane < 2 * NQ;
    const int q = (lane < NQ) ? lane : lane - NQ;
    const int sel = (lane < NQ) ? 0 : 1;
    const int scol = min(x0 + 4 * q, WW - 4);    // clamp: garbage cols masked later
    const float* pbase = (lane < NQ) ? in1 : in2;
    const float* sptr = pbase + (size_t)img * HH * WW + (size_t)y0 * WW + scol;
    float* swr = &sh[wid][0][sel][4 * q];        // buf stride = 2*SW floats

    const float* s1 = &sh[wid][0][0][0];
    const float* s2 = &sh[wid][0][1][0];

    float acc0[KW], acc1[KW], acc2[KW], acc3[KW], acc4[KW];
    #pragma unroll
    for (int i = 0; i < KW; ++i) {
        acc0[i] = 0.f; acc1[i] = 0.f; acc2[i] = 0.f; acc3[i] = 0.f; acc4[i] = 0.f;
    }

    double tsum = 0.0;

    // prime: row 0 -> buf 0
    if (stager) *(float4*)swr = *(const float4*)sptr;

    int yr = 0;
    while (yr < rows) {
        #pragma unroll
        for (int p = 0; p < KW; ++p, ++yr) {
            if (yr < rows) {
                const int buf = yr & 1;
                const int bo = buf * (2 * SW);   // float offset to buf

                // prefetch next row into registers (overlaps this row's VALU)
                float4 v;
                const bool pf = stager && (yr + 1 < rows);
                if (pf) v = *(const float4*)(sptr + (size_t)(yr + 1) * WW);

                // horizontal 11-tap conv of the 5 channels, products on the fly
                float h0 = 0.f, h1 = 0.f, h2 = 0.f, h3 = 0.f, h4 = 0.f;
                #pragma unroll
                for (int j = 0; j < KW; ++j) {
                    const float a = s1[bo + lane + j];
                    const float b = s2[bo + lane + j];
                    const float ga = gv[j] * a;
                    const float gb = gv[j] * b;
                    h0 += ga;
                    h1 += gb;
                    h2 = fmaf(ga, a, h2);
                    h3 = fmaf(gb, b, h3);
                    h4 = fmaf(ga, b, h4);
                }
                // vertical accumulate: at phase p, slot j lives in register (j+p)%11
                #pragma unroll
                for (int r2 = 0; r2 < KW; ++r2) {
                    const int j = (r2 - p + KW) % KW;
                    const float w = gv[HALO - j];
                    acc0[r2] = fmaf(w, h0, acc0[r2]);
                    acc1[r2] = fmaf(w, h1, acc1[r2]);
                    acc2[r2] = fmaf(w, h2, acc2[r2]);
                    acc3[r2] = fmaf(w, h3, acc3[r2]);
                    acc4[r2] = fmaf(w, h4, acc4[r2]);
                }
                // slot 0 (= register p) completes here -> output row yr-10
                if (yr >= HALO) {
                    const float mu1 = acc0[p], mu2 = acc1[p];
                    const float e11 = acc2[p], e22 = acc3[p], e12 = acc4[p];
                    const float s1q = fmaf(-mu1, mu1, e11);
                    const float s2q = fmaf(-mu2, mu2, e22);
                    const float s12 = fmaf(-mu1, mu2, e12);
                    const float den = __builtin_amdgcn_sqrtf(fabsf(s1q)) *
                                      __builtin_amdgcn_sqrtf(fabsf(s2q)) + C3V;
                    const float s = (s12 + C3V) * __builtin_amdgcn_rcpf(den);
                    if (lane < nx) tsum += (double)s;
                }
                acc0[p] = 0.f; acc1[p] = 0.f; acc2[p] = 0.f;
                acc3[p] = 0.f; acc4[p] = 0.f;

                // write prefetched row into the other buffer
                if (pf) *(float4*)(swr + (buf ^ 1) * (2 * SW)) = v;
            }
        }
    }

    // per-wave deterministic reduction; no cross-wave communication needed
    #pragma unroll
    for (int off = 32; off > 0; off >>= 1)
        tsum += __shfl_down(tsum, off, 64);
    if (lane == 0) {
        const int bid = (img * NBY + blockIdx.y) * NSX + strip;
        partials[bid] = tsum;
    }
}

// deterministic final reduce of the 4096 wave partials -> mean
__global__ __launch_bounds__(256) void ssim_reduce_kernel(
    const double* __restrict__ partials, float* __restrict__ out)
{
    __shared__ double sred[4];
    double s = 0.0;
    for (int i = threadIdx.x; i < NWAVE; i += 256) s += partials[i];
    #pragma unroll
    for (int off = 32; off > 0; off >>= 1)
        s += __shfl_down(s, off, 64);
    const int wid = threadIdx.x >> 6;
    const int lane = threadIdx.x & 63;
    if (lane == 0) sred[wid] = s;
    __syncthreads();
    if (threadIdx.x == 0) {
        const double total = sred[0] + sred[1] + sred[2] + sred[3];
        out[0] = (float)(total / ((double)BATCH * OH * OW));
    }
}

extern "C" void kernel_launch(void* const* d_in, const int* in_sizes, int n_in,
                              void* d_out, int out_size, void* d_ws, size_t ws_size,
                              hipStream_t stream) {
    const float* in1 = (const float*)d_in[0];
    const float* in2 = (const float*)d_in[1];
    const float* win = (const float*)d_in[2];
    float* out = (float*)d_out;
    double* partials = (double*)d_ws;   // 4096 doubles = 32 KB

    dim3 grid(NBX, NBY, BATCH);
    dim3 block(WPB * 64);
    ssim_strip_kernel<<<grid, block, 0, stream>>>(in1, in2, win, partials);
    ssim_reduce_kernel<<<1, 256, 0, stream>>>(partials, out);
}